// Round 6
// baseline (321.922 us; speedup 1.0000x reference)
//
#include <hip/hip_runtime.h>
#include <math.h>

#define D_MODEL 2048
#define NUM_HEADS 16
#define HEAD_DIM 128
#define BB 2
#define TT 2048
#define QKV_N 2304
#define KOFF 2048
#define VOFF 2176

typedef __attribute__((ext_vector_type(8))) short short8;
typedef __attribute__((ext_vector_type(4))) float f32x4;

static __device__ __forceinline__ short f2bf(float f) {
  union { float f; unsigned u; } x; x.f = f;
  unsigned r = (x.u + 0x7FFFu + ((x.u >> 16) & 1u)) >> 16;
  return (short)r;
}
static __device__ __forceinline__ float bf2f(unsigned short u) {
  return __uint_as_float(((unsigned)u) << 16);
}

#define GLD16(gp, lp)                                              \
  __builtin_amdgcn_global_load_lds(                                \
      (const __attribute__((address_space(1))) void*)(gp),         \
      (__attribute__((address_space(3))) void*)(lp), 16, 0, 0)

// 8-row-band column-major block swizzle: temporally adjacent blocks share an
// A band -> L2 locality (round 7: FETCH 89->46 MB).
static __device__ __forceinline__ void swizzle_xy(int& bx, int& by) {
  const int gx = gridDim.x;
  const int lin = blockIdx.y * gx + blockIdx.x;
  const int band = lin / (gx * 8);
  const int rem = lin - band * gx * 8;
  by = band * 8 + (rem & 7);
  bx = rem >> 3;
}

// ---------------------------------------------------------------------------
// GEMM1 fused: qkv = x @ W_qkv, RoPE in-epilogue, V written transposed.
// Round-0's 2-barrier BK=64 structure (71 us, best of 4 measured variants).
// Bank-conflict XOR swizzle kept (4.7M conflict cyc -> 0, verified).
// ---------------------------------------------------------------------------
__global__ __launch_bounds__(256) void gemm_qkv_rope(
    const short* __restrict__ A, const short* __restrict__ Bt,
    short* __restrict__ qkv, short* __restrict__ Vtb,
    const float* __restrict__ sin_t, const float* __restrict__ cos_t)
{
  __shared__ short As[2 * 128 * 32];  // [kc][m][32], 16 KB
  __shared__ short Bs[2 * 128 * 32];  // [kc][n][32], 16 KB
  const int K = D_MODEL;

  int bx, by;
  swizzle_xy(bx, by);

  const int tid = threadIdx.x;
  const int w = tid >> 6, l = tid & 63;
  const int quad = l >> 4, l16 = l & 15;
  const int wm = w >> 1, wn = w & 1;
  const int m0 = by * 128, n0 = bx * 128;

  f32x4 acc[4][4];
#pragma unroll
  for (int i = 0; i < 4; i++)
#pragma unroll
    for (int j = 0; j < 4; j++) acc[i][j] = (f32x4){0.f, 0.f, 0.f, 0.f};

  const int cswz = ((l & 3) ^ ((l >> 3) & 3)) * 8;
  const short* aA = A + (size_t)(m0 + w * 32 + (l >> 2)) * K + cswz;
  const short* aB = Bt + (size_t)(n0 + w * 32 + (l >> 2)) * K + cswz;
  short* lA = As + w * 1024;  // wave-uniform LDS bases
  short* lB = Bs + w * 1024;

  const int aswz = (quad ^ ((l16 >> 1) & 3)) * 8;
  const short* Ard = As + (size_t)(wm * 64 + l16) * 32 + aswz;
  const short* Brd = Bs + (size_t)(wn * 16 + l16) * 32 + aswz;

  for (int k0 = 0; k0 < K; k0 += 64) {
    __syncthreads();
#pragma unroll
    for (int h = 0; h < 2; h++) {  // two 32-k panels
      const int go = k0 + h * 32;
      const int lo = h * 4096;
      GLD16(aA + go, lA + lo);
      GLD16(aA + go + (size_t)16 * K, lA + lo + 512);
      GLD16(aB + go, lB + lo);
      GLD16(aB + go + (size_t)16 * K, lB + lo + 512);
    }
    __syncthreads();

#pragma unroll
    for (int kc = 0; kc < 2; kc++) {
      short8 af[4], bf[4];
#pragma unroll
      for (int mi = 0; mi < 4; mi++)
        af[mi] = *(const short8*)(Ard + kc * 4096 + mi * 512);
#pragma unroll
      for (int ni = 0; ni < 4; ni++)
        bf[ni] = *(const short8*)(Brd + kc * 4096 + ni * 1024);
#pragma unroll
      for (int mi = 0; mi < 4; mi++)
#pragma unroll
        for (int ni = 0; ni < 4; ni++)
          acc[mi][ni] =
              __builtin_amdgcn_mfma_f32_16x16x32_bf16(af[mi], bf[ni], acc[mi][ni], 0, 0, 0);
    }
  }

  const int colbase = wn * 16 + l16;      // in [0,32)
  const bool is_v = (n0 == VOFF);         // V head: no rope, transposed out

#pragma unroll
  for (int mi = 0; mi < 4; mi++) {
#pragma unroll
    for (int r = 0; r < 4; r++) {
      const int row = m0 + wm * 64 + mi * 16 + quad * 4 + r;
      const int b = row >> 11, t = row & (TT - 1);
#pragma unroll
      for (int ni = 0; ni < 2; ni++) {
        const int cloc = ni * 32 + colbase;   // in [0,64)
        const float c1 = acc[mi][ni][r];
        const float c2 = acc[mi][ni + 2][r];
        if (!is_v) {
          const float sn = sin_t[t * 64 + cloc];
          const float cs = cos_t[t * 64 + cloc];
          short* op = qkv + (size_t)row * QKV_N + n0 + cloc;
          op[0]  = f2bf(c1 * cs - c2 * sn);
          op[64] = f2bf(c2 * cs + c1 * sn);
        } else {
          Vtb[((size_t)(b * 128 + cloc) << 11) + t]      = f2bf(c1);
          Vtb[((size_t)(b * 128 + cloc + 64) << 11) + t] = f2bf(c2);
        }
      }
    }
  }
}

// ---------------------------------------------------------------------------
// GEMM2: out = attn_bf @ Wout_t^T, fp32 out. Round-0 BK=64 2-barrier + swizzle.
// ---------------------------------------------------------------------------
__global__ __launch_bounds__(256) void gemm_mfma_bt(
    const short* __restrict__ A, const short* __restrict__ Bt,
    float* __restrict__ C, int M, int N, int K)
{
  __shared__ short As[2 * 128 * 32];
  __shared__ short Bs[2 * 128 * 32];

  int bx, by;
  swizzle_xy(bx, by);

  const int tid = threadIdx.x;
  const int w = tid >> 6, l = tid & 63;
  const int quad = l >> 4, l16 = l & 15;
  const int wm = w >> 1, wn = w & 1;
  const int m0 = by * 128, n0 = bx * 128;

  f32x4 acc[4][4];
#pragma unroll
  for (int i = 0; i < 4; i++)
#pragma unroll
    for (int j = 0; j < 4; j++) acc[i][j] = (f32x4){0.f, 0.f, 0.f, 0.f};

  const int cswz = ((l & 3) ^ ((l >> 3) & 3)) * 8;
  const short* aA = A + (size_t)(m0 + w * 32 + (l >> 2)) * K + cswz;
  const short* aB = Bt + (size_t)(n0 + w * 32 + (l >> 2)) * K + cswz;
  short* lA = As + w * 1024;
  short* lB = Bs + w * 1024;

  const int aswz = (quad ^ ((l16 >> 1) & 3)) * 8;
  const short* Ard = As + (size_t)(wm * 64 + l16) * 32 + aswz;
  const short* Brd = Bs + (size_t)(wn * 64 + l16) * 32 + aswz;

  for (int k0 = 0; k0 < K; k0 += 64) {
    __syncthreads();
#pragma unroll
    for (int h = 0; h < 2; h++) {
      const int go = k0 + h * 32;
      const int lo = h * 4096;
      GLD16(aA + go, lA + lo);
      GLD16(aA + go + (size_t)16 * K, lA + lo + 512);
      GLD16(aB + go, lB + lo);
      GLD16(aB + go + (size_t)16 * K, lB + lo + 512);
    }
    __syncthreads();

#pragma unroll
    for (int kc = 0; kc < 2; kc++) {
      short8 af[4], bf[4];
#pragma unroll
      for (int mi = 0; mi < 4; mi++)
        af[mi] = *(const short8*)(Ard + kc * 4096 + mi * 512);
#pragma unroll
      for (int ni = 0; ni < 4; ni++)
        bf[ni] = *(const short8*)(Brd + kc * 4096 + ni * 512);
#pragma unroll
      for (int mi = 0; mi < 4; mi++)
#pragma unroll
        for (int ni = 0; ni < 4; ni++)
          acc[mi][ni] =
              __builtin_amdgcn_mfma_f32_16x16x32_bf16(af[mi], bf[ni], acc[mi][ni], 0, 0, 0);
    }
  }

#pragma unroll
  for (int mi = 0; mi < 4; mi++) {
#pragma unroll
    for (int ni = 0; ni < 4; ni++) {
#pragma unroll
      for (int r = 0; r < 4; r++) {
        const int row = m0 + wm * 64 + mi * 16 + quad * 4 + r;
        const int col = n0 + wn * 64 + ni * 16 + l16;
        C[(size_t)row * N + col] = acc[mi][ni][r];
      }
    }
  }
}

// ---------------------------------------------------------------------------
// Fused prep: convert x -> bf16, transpose+convert W_qkv and W_out.
// ---------------------------------------------------------------------------
#define XB_BLOCKS 8192                 // 4096*2048/4/256
#define WQ_BLOCKS (72 * 64)            // (2304/32)*(2048/32)
#define WO_BLOCKS (64 * 64)

__global__ __launch_bounds__(256) void prep_all(
    const float* __restrict__ x, short* __restrict__ xb,
    const float* __restrict__ Wq, short* __restrict__ Wqt,
    const float* __restrict__ Wo, short* __restrict__ Wot)
{
  const int bid = blockIdx.x;
  const int tid = threadIdx.x;

  if (bid < XB_BLOCKS) {
    const size_t i4 = (size_t)bid * 256 + tid;
    float4 v = *(const float4*)(x + i4 * 4);
    short4 o;
    o.x = f2bf(v.x); o.y = f2bf(v.y); o.z = f2bf(v.z); o.w = f2bf(v.w);
    *(short4*)(xb + i4 * 4) = o;
    return;
  }

  __shared__ float t[32][33];
  const float* W;
  short* Wt;
  int N, tile, ntx;
  if (bid < XB_BLOCKS + WQ_BLOCKS) {
    tile = bid - XB_BLOCKS; W = Wq; Wt = Wqt; N = QKV_N; ntx = 72;
  } else {
    tile = bid - XB_BLOCKS - WQ_BLOCKS; W = Wo; Wt = Wot; N = D_MODEL; ntx = 64;
  }
  const int K = D_MODEL;
  const int bx = tile % ntx, byy = tile / ntx;
  const int tx = tid & 31, ty = tid >> 5;
  const int n0 = bx * 32, k0 = byy * 32;
#pragma unroll
  for (int j = 0; j < 4; j++)
    t[ty + j * 8][tx] = W[(size_t)(k0 + ty + j * 8) * N + n0 + tx];
  __syncthreads();
#pragma unroll
  for (int j = 0; j < 4; j++)
    Wt[(size_t)(n0 + ty + j * 8) * K + k0 + tx] = f2bf(t[tx][ty + j * 8]);
}

// ---------------------------------------------------------------------------
// Flash MQA attention. T14 async-STAGE split (K/V for tile st+1 loaded into
// registers under tile st's compute). Round 5 proved the structure correct
// but the default VGPR cap (68) spilled the 32-reg prefetch to scratch
// (WRITE_SIZE 138MB, occupancy 16.7%, 104us). Fix: __launch_bounds__(256,1)
// relaxes the cap (~112 live regs fit; occupancy stays LDS-capped at
// 3 blocks/CU so nothing is traded). setprio dropped (m190 null regime:
// 4-wave barrier-lockstep block).
// ---------------------------------------------------------------------------
#define KSTR 136
#define VSTR 72
#define PSTR 72

__global__ __launch_bounds__(256, 1) void attn_mfma(
    const short* __restrict__ qkv, const short* __restrict__ Vtb,
    const int* __restrict__ doc_ids, short* __restrict__ attn_out)
{
  __shared__ short Ks[64 * KSTR];
  __shared__ short Vt[128 * VSTR];
  __shared__ short Pbuf[4 * 16 * PSTR];
  __shared__ int doc_s[64];
  __shared__ int st_lo_s;

  const int qt = blockIdx.x, h = blockIdx.y, b = blockIdx.z;
  const int q0 = qt * 64;
  const int tid = threadIdx.x;
  const int w = tid >> 6;
  const int lane = tid & 63;
  const int quad = lane >> 4, l16 = lane & 15;

  const short* qp = qkv + (size_t)(b * TT + q0 + w * 16 + l16) * QKV_N
                    + h * HEAD_DIM + quad * 8;
  short8 Qf[4];
#pragma unroll
  for (int kc = 0; kc < 4; kc++) Qf[kc] = *(const short8*)(qp + kc * 32);

  const int docmin_q = doc_ids[b * TT + q0];
  const int docmax_q = doc_ids[b * TT + q0 + 63];

  // wave-parallel skip-prefix scan: first st with dmax_s >= docmin_q.
  // Clamped index (no OOB even if speculated); st=qt lane guaranteed ok.
  if (tid < 64) {
    const int sti = tid <= qt ? tid : qt;
    int ok = doc_ids[b * TT + sti * 64 + 63] >= docmin_q;
    unsigned long long m = __ballot(ok);
    if (tid == 0) st_lo_s = (int)__ffsll(m) - 1;
  }

  int qg[4], mydoc[4];
  float l_i[4];
#pragma unroll
  for (int r = 0; r < 4; r++) {
    qg[r] = q0 + w * 16 + quad * 4 + r;
    mydoc[r] = doc_ids[b * TT + qg[r]];
    l_i[r] = 0.f;
  }
  f32x4 O[8];
#pragma unroll
  for (int v8 = 0; v8 < 8; v8++) O[v8] = (f32x4){0.f, 0.f, 0.f, 0.f};

  short* Pw = Pbuf + w * 16 * PSTR;
  const float scale = 0.08838834764831844f;

  __syncthreads();
  const int st_lo = st_lo_s;

  // T14 register staging: tile st's K/V live in regs across the prev barrier
  int4 kreg[4], vreg[4];
  const int kro = tid >> 4, kse = (tid & 15) * 8;   // K: row offset, col seg
  const int vro = tid >> 3, vse = (tid & 7) * 8;    // V: n offset, col seg
  auto loadKV = [&](int s0n) {
#pragma unroll
    for (int i = 0; i < 4; i++)
      kreg[i] = *(const int4*)(qkv + (size_t)(b * TT + s0n + i * 16 + kro) * QKV_N + KOFF + kse);
#pragma unroll
    for (int i = 0; i < 4; i++)
      vreg[i] = *(const int4*)(Vtb + ((size_t)(b * 128 + i * 32 + vro) << 11) + s0n + vse);
  };

  loadKV(st_lo * 64);

  for (int st = st_lo; st <= qt; st++) {
    const int s0 = st * 64;
    const bool full = (st < qt) && (doc_ids[b * TT + s0] == docmax_q);

    __syncthreads();   // prev tile's LDS reads complete
#pragma unroll
    for (int i = 0; i < 4; i++)
      *(int4*)(Ks + (i * 16 + kro) * KSTR + kse) = kreg[i];
#pragma unroll
    for (int i = 0; i < 4; i++)
      *(int4*)(Vt + (i * 32 + vro) * VSTR + vse) = vreg[i];
    if (!full && tid < 64) doc_s[tid] = doc_ids[b * TT + s0 + tid];
    if (st < qt) loadKV(s0 + 64);   // prefetch next tile under compute
    __syncthreads();

    f32x4 S[4];
#pragma unroll
    for (int ns = 0; ns < 4; ns++) {
      f32x4 acc = (f32x4){0.f, 0.f, 0.f, 0.f};
      const short* kr = Ks + (ns * 16 + l16) * KSTR + quad * 8;
#pragma unroll
      for (int kc = 0; kc < 4; kc++) {
        short8 kf = *(const short8*)(kr + kc * 32);
        acc = __builtin_amdgcn_mfma_f32_16x16x32_bf16(Qf[kc], kf, acc, 0, 0, 0);
      }
      S[ns] = acc;
    }

    if (full) {
#pragma unroll
      for (int ns = 0; ns < 4; ns++)
#pragma unroll
        for (int r = 0; r < 4; r++) {
          const float p = __expf(S[ns][r] * scale);
          l_i[r] += p;
          Pw[(quad * 4 + r) * PSTR + ns * 16 + l16] = f2bf(p);
        }
    } else {
#pragma unroll
      for (int ns = 0; ns < 4; ns++) {
        const int s_loc = ns * 16 + l16;
        const int sg = s0 + s_loc;
        const int sdoc = doc_s[s_loc];
#pragma unroll
        for (int r = 0; r < 4; r++) {
          const bool ok = (sg <= qg[r]) && (sdoc == mydoc[r]);
          const float p = ok ? __expf(S[ns][r] * scale) : 0.f;
          l_i[r] += p;
          Pw[(quad * 4 + r) * PSTR + ns * 16 + l16] = f2bf(p);
        }
      }
    }

#pragma unroll
    for (int ks = 0; ks < 2; ks++) {
      short8 pf = *(const short8*)(Pw + l16 * PSTR + ks * 32 + quad * 8);
#pragma unroll
      for (int v8 = 0; v8 < 8; v8++) {
        short8 vf = *(const short8*)(Vt + (v8 * 16 + l16) * VSTR + ks * 32 + quad * 8);
        O[v8] = __builtin_amdgcn_mfma_f32_16x16x32_bf16(pf, vf, O[v8], 0, 0, 0);
      }
    }
  }

#pragma unroll
  for (int off = 8; off >= 1; off >>= 1)
#pragma unroll
    for (int r = 0; r < 4; r++) l_i[r] += __shfl_xor(l_i[r], off);

#pragma unroll
  for (int r = 0; r < 4; r++) {
    const float inv = 1.f / l_i[r];
    short* op = attn_out + (size_t)(b * TT + qg[r]) * D_MODEL + h * HEAD_DIM + l16;
#pragma unroll
    for (int v8 = 0; v8 < 8; v8++)
      op[v8 * 16] = f2bf(O[v8][r] * inv);
  }
}

// ---------------------------------------------------------------------------
extern "C" void kernel_launch(void* const* d_in, const int* in_sizes, int n_in,
                              void* d_out, int out_size, void* d_ws, size_t ws_size,
                              hipStream_t stream)
{
  const float* x     = (const float*)d_in[0];
  const float* sin_t = (const float*)d_in[1];
  const float* cos_t = (const float*)d_in[2];
  const int*   doc   = (const int*)  d_in[3];
  const float* W_qkv = (const float*)d_in[4];
  const float* W_out = (const float*)d_in[5];
  float* out = (float*)d_out;

  const int M = BB * TT;  // 4096

  char* p = (char*)d_ws;
  short* qkv_bf = (short*)p; p += (size_t)M * QKV_N * 2;
  short* xb     = (short*)p; p += (size_t)M * D_MODEL * 2;
  short* attn_bf = xb;  // alias: xb dead after GEMM1
  short* Vtb    = (short*)p; p += (size_t)BB * 128 * TT * 2;
  short* Wqkv_t = (short*)p; p += (size_t)QKV_N * D_MODEL * 2;
  short* Wout_t = (short*)p;

  // fused preps
  prep_all<<<XB_BLOCKS + WQ_BLOCKS + WO_BLOCKS, 256, 0, stream>>>(
      x, xb, W_qkv, Wqkv_t, W_out, Wout_t);

  // GEMM1 fused with RoPE + V-transpose epilogue (BK=64, 2-barrier)
  {
    dim3 grid(QKV_N / 128, M / 128);
    gemm_qkv_rope<<<grid, 256, 0, stream>>>(xb, Wqkv_t, qkv_bf, Vtb, sin_t, cos_t);
  }
  // flash attention (T14 prefetch, no-spill)
  {
    dim3 grid(TT / 64, NUM_HEADS, BB);
    attn_mfma<<<grid, 256, 0, stream>>>(qkv_bf, Vtb, doc, attn_bf);
  }
  // GEMM2 (BK=64, 2-barrier)
  {
    dim3 grid(D_MODEL / 128, M / 128);
    gemm_mfma_bt<<<grid, 256, 0, stream>>>(attn_bf, Wout_t, out, M, D_MODEL, D_MODEL);
  }
}

// Round 7
// 267.833 us; speedup vs baseline: 1.2019x; 1.2019x over previous
//
#include <hip/hip_runtime.h>
#include <math.h>

#define D_MODEL 2048
#define NUM_HEADS 16
#define HEAD_DIM 128
#define BB 2
#define TT 2048
#define QKV_N 2304
#define KOFF 2048
#define VOFF 2176

typedef __attribute__((ext_vector_type(8))) short short8;
typedef __attribute__((ext_vector_type(4))) float f32x4;

static __device__ __forceinline__ short f2bf(float f) {
  union { float f; unsigned u; } x; x.f = f;
  unsigned r = (x.u + 0x7FFFu + ((x.u >> 16) & 1u)) >> 16;
  return (short)r;
}

#define GLD16(gp, lp)                                              \
  __builtin_amdgcn_global_load_lds(                                \
      (const __attribute__((address_space(1))) void*)(gp),         \
      (__attribute__((address_space(3))) void*)(lp), 16, 0, 0)

// 8-row-band column-major block swizzle: temporally adjacent blocks share an
// A band -> L2 locality (round 7: FETCH 89->46 MB).
static __device__ __forceinline__ void swizzle_xy(int& bx, int& by) {
  const int gx = gridDim.x;
  const int lin = blockIdx.y * gx + blockIdx.x;
  const int band = lin / (gx * 8);
  const int rem = lin - band * gx * 8;
  by = band * 8 + (rem & 7);
  bx = rem >> 3;
}

// ---------------------------------------------------------------------------
// GEMM1 fused: qkv = x @ W_qkv, RoPE in-epilogue, V written transposed.
// Round-0's 2-barrier BK=64 structure (71 us, best of 4 measured variants).
// Bank-conflict XOR swizzle kept (4.7M conflict cyc -> 0, verified).
// ---------------------------------------------------------------------------
__global__ __launch_bounds__(256) void gemm_qkv_rope(
    const short* __restrict__ A, const short* __restrict__ Bt,
    short* __restrict__ qkv, short* __restrict__ Vtb,
    const float* __restrict__ sin_t, const float* __restrict__ cos_t)
{
  __shared__ short As[2 * 128 * 32];  // [kc][m][32], 16 KB
  __shared__ short Bs[2 * 128 * 32];  // [kc][n][32], 16 KB
  const int K = D_MODEL;

  int bx, by;
  swizzle_xy(bx, by);

  const int tid = threadIdx.x;
  const int w = tid >> 6, l = tid & 63;
  const int quad = l >> 4, l16 = l & 15;
  const int wm = w >> 1, wn = w & 1;
  const int m0 = by * 128, n0 = bx * 128;

  f32x4 acc[4][4];
#pragma unroll
  for (int i = 0; i < 4; i++)
#pragma unroll
    for (int j = 0; j < 4; j++) acc[i][j] = (f32x4){0.f, 0.f, 0.f, 0.f};

  const int cswz = ((l & 3) ^ ((l >> 3) & 3)) * 8;
  const short* aA = A + (size_t)(m0 + w * 32 + (l >> 2)) * K + cswz;
  const short* aB = Bt + (size_t)(n0 + w * 32 + (l >> 2)) * K + cswz;
  short* lA = As + w * 1024;  // wave-uniform LDS bases
  short* lB = Bs + w * 1024;

  const int aswz = (quad ^ ((l16 >> 1) & 3)) * 8;
  const short* Ard = As + (size_t)(wm * 64 + l16) * 32 + aswz;
  const short* Brd = Bs + (size_t)(wn * 16 + l16) * 32 + aswz;

  for (int k0 = 0; k0 < K; k0 += 64) {
    __syncthreads();
#pragma unroll
    for (int h = 0; h < 2; h++) {  // two 32-k panels
      const int go = k0 + h * 32;
      const int lo = h * 4096;
      GLD16(aA + go, lA + lo);
      GLD16(aA + go + (size_t)16 * K, lA + lo + 512);
      GLD16(aB + go, lB + lo);
      GLD16(aB + go + (size_t)16 * K, lB + lo + 512);
    }
    __syncthreads();

#pragma unroll
    for (int kc = 0; kc < 2; kc++) {
      short8 af[4], bf[4];
#pragma unroll
      for (int mi = 0; mi < 4; mi++)
        af[mi] = *(const short8*)(Ard + kc * 4096 + mi * 512);
#pragma unroll
      for (int ni = 0; ni < 4; ni++)
        bf[ni] = *(const short8*)(Brd + kc * 4096 + ni * 1024);
#pragma unroll
      for (int mi = 0; mi < 4; mi++)
#pragma unroll
        for (int ni = 0; ni < 4; ni++)
          acc[mi][ni] =
              __builtin_amdgcn_mfma_f32_16x16x32_bf16(af[mi], bf[ni], acc[mi][ni], 0, 0, 0);
    }
  }

  const int colbase = wn * 16 + l16;      // in [0,32)
  const bool is_v = (n0 == VOFF);         // V head: no rope, transposed out

#pragma unroll
  for (int mi = 0; mi < 4; mi++) {
#pragma unroll
    for (int r = 0; r < 4; r++) {
      const int row = m0 + wm * 64 + mi * 16 + quad * 4 + r;
      const int b = row >> 11, t = row & (TT - 1);
#pragma unroll
      for (int ni = 0; ni < 2; ni++) {
        const int cloc = ni * 32 + colbase;   // in [0,64)
        const float c1 = acc[mi][ni][r];
        const float c2 = acc[mi][ni + 2][r];
        if (!is_v) {
          const float sn = sin_t[t * 64 + cloc];
          const float cs = cos_t[t * 64 + cloc];
          short* op = qkv + (size_t)row * QKV_N + n0 + cloc;
          op[0]  = f2bf(c1 * cs - c2 * sn);
          op[64] = f2bf(c2 * cs + c1 * sn);
        } else {
          Vtb[((size_t)(b * 128 + cloc) << 11) + t]      = f2bf(c1);
          Vtb[((size_t)(b * 128 + cloc + 64) << 11) + t] = f2bf(c2);
        }
      }
    }
  }
}

// ---------------------------------------------------------------------------
// GEMM2: out = attn_bf @ Wout_t^T, fp32 out. Round-0 BK=64 2-barrier + swizzle.
// ---------------------------------------------------------------------------
__global__ __launch_bounds__(256) void gemm_mfma_bt(
    const short* __restrict__ A, const short* __restrict__ Bt,
    float* __restrict__ C, int M, int N, int K)
{
  __shared__ short As[2 * 128 * 32];
  __shared__ short Bs[2 * 128 * 32];

  int bx, by;
  swizzle_xy(bx, by);

  const int tid = threadIdx.x;
  const int w = tid >> 6, l = tid & 63;
  const int quad = l >> 4, l16 = l & 15;
  const int wm = w >> 1, wn = w & 1;
  const int m0 = by * 128, n0 = bx * 128;

  f32x4 acc[4][4];
#pragma unroll
  for (int i = 0; i < 4; i++)
#pragma unroll
    for (int j = 0; j < 4; j++) acc[i][j] = (f32x4){0.f, 0.f, 0.f, 0.f};

  const int cswz = ((l & 3) ^ ((l >> 3) & 3)) * 8;
  const short* aA = A + (size_t)(m0 + w * 32 + (l >> 2)) * K + cswz;
  const short* aB = Bt + (size_t)(n0 + w * 32 + (l >> 2)) * K + cswz;
  short* lA = As + w * 1024;
  short* lB = Bs + w * 1024;

  const int aswz = (quad ^ ((l16 >> 1) & 3)) * 8;
  const short* Ard = As + (size_t)(wm * 64 + l16) * 32 + aswz;
  const short* Brd = Bs + (size_t)(wn * 64 + l16) * 32 + aswz;

  for (int k0 = 0; k0 < K; k0 += 64) {
    __syncthreads();
#pragma unroll
    for (int h = 0; h < 2; h++) {
      const int go = k0 + h * 32;
      const int lo = h * 4096;
      GLD16(aA + go, lA + lo);
      GLD16(aA + go + (size_t)16 * K, lA + lo + 512);
      GLD16(aB + go, lB + lo);
      GLD16(aB + go + (size_t)16 * K, lB + lo + 512);
    }
    __syncthreads();

#pragma unroll
    for (int kc = 0; kc < 2; kc++) {
      short8 af[4], bf[4];
#pragma unroll
      for (int mi = 0; mi < 4; mi++)
        af[mi] = *(const short8*)(Ard + kc * 4096 + mi * 512);
#pragma unroll
      for (int ni = 0; ni < 4; ni++)
        bf[ni] = *(const short8*)(Brd + kc * 4096 + ni * 512);
#pragma unroll
      for (int mi = 0; mi < 4; mi++)
#pragma unroll
        for (int ni = 0; ni < 4; ni++)
          acc[mi][ni] =
              __builtin_amdgcn_mfma_f32_16x16x32_bf16(af[mi], bf[ni], acc[mi][ni], 0, 0, 0);
    }
  }

#pragma unroll
  for (int mi = 0; mi < 4; mi++) {
#pragma unroll
    for (int ni = 0; ni < 4; ni++) {
#pragma unroll
      for (int r = 0; r < 4; r++) {
        const int row = m0 + wm * 64 + mi * 16 + quad * 4 + r;
        const int col = n0 + wn * 64 + ni * 16 + l16;
        C[(size_t)row * N + col] = acc[mi][ni][r];
      }
    }
  }
}

// ---------------------------------------------------------------------------
// Fused prep: convert x -> bf16, transpose+convert W_qkv and W_out.
// ---------------------------------------------------------------------------
#define XB_BLOCKS 8192                 // 4096*2048/4/256
#define WQ_BLOCKS (72 * 64)            // (2304/32)*(2048/32)
#define WO_BLOCKS (64 * 64)

__global__ __launch_bounds__(256) void prep_all(
    const float* __restrict__ x, short* __restrict__ xb,
    const float* __restrict__ Wq, short* __restrict__ Wqt,
    const float* __restrict__ Wo, short* __restrict__ Wot)
{
  const int bid = blockIdx.x;
  const int tid = threadIdx.x;

  if (bid < XB_BLOCKS) {
    const size_t i4 = (size_t)bid * 256 + tid;
    float4 v = *(const float4*)(x + i4 * 4);
    short4 o;
    o.x = f2bf(v.x); o.y = f2bf(v.y); o.z = f2bf(v.z); o.w = f2bf(v.w);
    *(short4*)(xb + i4 * 4) = o;
    return;
  }

  __shared__ float t[32][33];
  const float* W;
  short* Wt;
  int N, tile, ntx;
  if (bid < XB_BLOCKS + WQ_BLOCKS) {
    tile = bid - XB_BLOCKS; W = Wq; Wt = Wqt; N = QKV_N; ntx = 72;
  } else {
    tile = bid - XB_BLOCKS - WQ_BLOCKS; W = Wo; Wt = Wot; N = D_MODEL; ntx = 64;
  }
  const int K = D_MODEL;
  const int bx = tile % ntx, byy = tile / ntx;
  const int tx = tid & 31, ty = tid >> 5;
  const int n0 = bx * 32, k0 = byy * 32;
#pragma unroll
  for (int j = 0; j < 4; j++)
    t[ty + j * 8][tx] = W[(size_t)(k0 + ty + j * 8) * N + n0 + tx];
  __syncthreads();
#pragma unroll
  for (int j = 0; j < 4; j++)
    Wt[(size_t)(n0 + ty + j * 8) * K + k0 + tx] = f2bf(t[tx][ty + j * 8]);
}

// ---------------------------------------------------------------------------
// Flash MQA attention, round-0 structure with GLD16 staging (round 13).
// T14 reg-staging arc (rounds 5-6) reverted: 138MB excess writes, 104us.
// Change vs round-0: K/V staged via global_load_lds (no per-thread global->
// reg->ds_write round trip, fewer registers, no staging ds_writes). Linear
// LDS rows (K:128, V:64 shorts) with rule-21 both-sides XOR chunk swizzle:
// LDS[r][c] = src[r][c ^ (r&7)]; reads XOR the same -> identity, and read
// banks balanced (8 lanes / 4-bank window = b128 minimum, conflict-free).
// ---------------------------------------------------------------------------
#define PSTR 72

__global__ __launch_bounds__(256) void attn_mfma(
    const short* __restrict__ qkv, const short* __restrict__ Vtb,
    const int* __restrict__ doc_ids, short* __restrict__ attn_out)
{
  __shared__ short Ks[64 * 128];     // 16 KB, linear + chunk-XOR
  __shared__ short Vt[128 * 64];     // 16 KB, linear + chunk-XOR
  __shared__ short Pbuf[4 * 16 * PSTR];
  __shared__ int doc_s[64];

  const int qt = blockIdx.x, h = blockIdx.y, b = blockIdx.z;
  const int q0 = qt * 64;
  const int tid = threadIdx.x;
  const int w = tid >> 6;
  const int lane = tid & 63;
  const int quad = lane >> 4, l16 = lane & 15;

  const short* qp = qkv + (size_t)(b * TT + q0 + w * 16 + l16) * QKV_N
                    + h * HEAD_DIM + quad * 8;
  short8 Qf[4];
#pragma unroll
  for (int kc = 0; kc < 4; kc++) Qf[kc] = *(const short8*)(qp + kc * 32);

  const int docmin_q = doc_ids[b * TT + q0];
  const int docmax_q = doc_ids[b * TT + q0 + 63];

  int qg[4], mydoc[4];
  float l_i[4];
#pragma unroll
  for (int r = 0; r < 4; r++) {
    qg[r] = q0 + w * 16 + quad * 4 + r;
    mydoc[r] = doc_ids[b * TT + qg[r]];
    l_i[r] = 0.f;
  }
  f32x4 O[8];
#pragma unroll
  for (int v8 = 0; v8 < 8; v8++) O[v8] = (f32x4){0.f, 0.f, 0.f, 0.f};

  short* Pw = Pbuf + w * 16 * PSTR;
  const float scale = 0.08838834764831844f;

  // per-lane swizzled read-column tables (constant across tiles)
  const int x7 = l16 & 7;
  int kcol[4], vcol[2];
#pragma unroll
  for (int kc = 0; kc < 4; kc++) kcol[kc] = ((kc * 4 + quad) ^ x7) * 8;
#pragma unroll
  for (int ks = 0; ks < 2; ks++) vcol[ks] = ((ks * 4 + quad) ^ x7) * 8;

  for (int st = 0; st <= qt; st++) {
    const int s0 = st * 64;
    const int dmin_s = doc_ids[b * TT + s0];
    const int dmax_s = doc_ids[b * TT + s0 + 63];
    if (dmax_s < docmin_q) continue;
    const bool full = (st < qt) && (dmin_s == docmax_q);

    __syncthreads();
    // K: 16 KB = 16 x 1KB issues, 4 per wave. Issue f covers rows 4f..4f+3;
    // lane -> row 4f+(lane>>4), chunk lane&15; source chunk pre-XOR'd.
#pragma unroll
    for (int j = 0; j < 4; j++) {
      const int f = w * 4 + j;
      const int rg = f * 4 + (lane >> 4);
      GLD16(qkv + (size_t)(b * TT + s0 + rg) * QKV_N + KOFF
                + (((lane & 15) ^ (rg & 7)) * 8),
            Ks + f * 512);
    }
    // V: 16 KB = 16 x 1KB issues, 4 per wave. Issue f covers n 8f..8f+7;
    // lane -> n 8f+(lane>>3), chunk lane&7; n&7 == lane>>3.
#pragma unroll
    for (int j = 0; j < 4; j++) {
      const int f = w * 4 + j;
      const int n = f * 8 + (lane >> 3);
      GLD16(Vtb + (((size_t)(b * 128 + n)) << 11) + s0
                + (((lane & 7) ^ (lane >> 3)) * 8),
            Vt + f * 512);
    }
    if (!full && tid < 64) doc_s[tid] = doc_ids[b * TT + s0 + tid];
    __syncthreads();   // drains vmcnt: staging landed

    f32x4 S[4];
#pragma unroll
    for (int ns = 0; ns < 4; ns++) {
      f32x4 acc = (f32x4){0.f, 0.f, 0.f, 0.f};
      const short* krow = Ks + (ns * 16 + l16) * 128;
#pragma unroll
      for (int kc = 0; kc < 4; kc++) {
        short8 kf = *(const short8*)(krow + kcol[kc]);
        acc = __builtin_amdgcn_mfma_f32_16x16x32_bf16(Qf[kc], kf, acc, 0, 0, 0);
      }
      S[ns] = acc;
    }

    if (full) {
#pragma unroll
      for (int ns = 0; ns < 4; ns++)
#pragma unroll
        for (int r = 0; r < 4; r++) {
          const float p = __expf(S[ns][r] * scale);
          l_i[r] += p;
          Pw[(quad * 4 + r) * PSTR + ns * 16 + l16] = f2bf(p);
        }
    } else {
#pragma unroll
      for (int ns = 0; ns < 4; ns++) {
        const int s_loc = ns * 16 + l16;
        const int sg = s0 + s_loc;
        const int sdoc = doc_s[s_loc];
#pragma unroll
        for (int r = 0; r < 4; r++) {
          const bool ok = (sg <= qg[r]) && (sdoc == mydoc[r]);
          const float p = ok ? __expf(S[ns][r] * scale) : 0.f;
          l_i[r] += p;
          Pw[(quad * 4 + r) * PSTR + ns * 16 + l16] = f2bf(p);
        }
      }
    }

#pragma unroll
    for (int ks = 0; ks < 2; ks++) {
      short8 pf = *(const short8*)(Pw + l16 * PSTR + ks * 32 + quad * 8);
#pragma unroll
      for (int v8 = 0; v8 < 8; v8++) {
        short8 vf = *(const short8*)(Vt + (v8 * 16 + l16) * 64 + vcol[ks]);
        O[v8] = __builtin_amdgcn_mfma_f32_16x16x32_bf16(pf, vf, O[v8], 0, 0, 0);
      }
    }
  }

#pragma unroll
  for (int off = 8; off >= 1; off >>= 1)
#pragma unroll
    for (int r = 0; r < 4; r++) l_i[r] += __shfl_xor(l_i[r], off);

#pragma unroll
  for (int r = 0; r < 4; r++) {
    const float inv = 1.f / l_i[r];
    short* op = attn_out + (size_t)(b * TT + qg[r]) * D_MODEL + h * HEAD_DIM + l16;
#pragma unroll
    for (int v8 = 0; v8 < 8; v8++)
      op[v8 * 16] = f2bf(O[v8][r] * inv);
  }
}

// ---------------------------------------------------------------------------
extern "C" void kernel_launch(void* const* d_in, const int* in_sizes, int n_in,
                              void* d_out, int out_size, void* d_ws, size_t ws_size,
                              hipStream_t stream)
{
  const float* x     = (const float*)d_in[0];
  const float* sin_t = (const float*)d_in[1];
  const float* cos_t = (const float*)d_in[2];
  const int*   doc   = (const int*)  d_in[3];
  const float* W_qkv = (const float*)d_in[4];
  const float* W_out = (const float*)d_in[5];
  float* out = (float*)d_out;

  const int M = BB * TT;  // 4096

  char* p = (char*)d_ws;
  short* qkv_bf = (short*)p; p += (size_t)M * QKV_N * 2;
  short* xb     = (short*)p; p += (size_t)M * D_MODEL * 2;
  short* attn_bf = xb;  // alias: xb dead after GEMM1
  short* Vtb    = (short*)p; p += (size_t)BB * 128 * TT * 2;
  short* Wqkv_t = (short*)p; p += (size_t)QKV_N * D_MODEL * 2;
  short* Wout_t = (short*)p;

  // fused preps
  prep_all<<<XB_BLOCKS + WQ_BLOCKS + WO_BLOCKS, 256, 0, stream>>>(
      x, xb, W_qkv, Wqkv_t, W_out, Wout_t);

  // GEMM1 fused with RoPE + V-transpose epilogue (BK=64, 2-barrier)
  {
    dim3 grid(QKV_N / 128, M / 128);
    gemm_qkv_rope<<<grid, 256, 0, stream>>>(xb, Wqkv_t, qkv_bf, Vtb, sin_t, cos_t);
  }
  // flash attention (GLD16-staged K/V, XOR-swizzled reads)
  {
    dim3 grid(TT / 64, NUM_HEADS, BB);
    attn_mfma<<<grid, 256, 0, stream>>>(qkv_bf, Vtb, doc, attn_bf);
  }
  // GEMM2 (BK=64, 2-barrier)
  {
    dim3 grid(D_MODEL / 128, M / 128);
    gemm_mfma_bt<<<grid, 256, 0, stream>>>(attn_bf, Wout_t, out, M, D_MODEL, D_MODEL);
  }
}